// Round 2
// baseline (3256.919 us; speedup 1.0000x reference)
//
#include <hip/hip_runtime.h>

typedef unsigned int  u32;
typedef unsigned short u16;
typedef unsigned long long u64;
typedef _Float16 half8 __attribute__((ext_vector_type(8)));
typedef short   short8 __attribute__((ext_vector_type(8)));
typedef float   f32x4  __attribute__((ext_vector_type(4)));
typedef u64     u64x2  __attribute__((ext_vector_type(2)));

#define T_LEN 512
#define BATCH 64
#define EDIM  256
#define HDIM  256
#define G4    1024   // 4*H gate rows

// ---------- numeric helpers ----------
static __device__ __forceinline__ u16 f2bf(float f) {
  u32 u = __builtin_bit_cast(u32, f);
  u = (u + 0x7fffu + ((u >> 16) & 1u)) >> 16;   // RTNE
  return (u16)u;
}
static __device__ __forceinline__ u16 f2h(float a) {
  _Float16 ha = (_Float16)a;
  return __builtin_bit_cast(u16, ha);
}
static __device__ __forceinline__ float h2f(u16 a) {
  return (float)__builtin_bit_cast(_Float16, a);
}
static __device__ __forceinline__ float sigf(float x) {
  return 1.0f / (1.0f + __expf(-x));
}
static __device__ __forceinline__ float tanhfast(float x) {
  return 2.0f / (1.0f + __expf(-2.0f * x)) - 1.0f;
}

// ---------- kernel 1: pack W_hh_f into f16 MFMA A-frag order -----------------
// Wf[mt][kt][lane][j]: flat ((mt*8+kt)*64+lane)*8+j; value =
// W[mt*16+(lane&15)][kt*32+(lane>>4)*8+j].
// Also zero the t=0 h-exchange parity buffer and the 16 step flags (must be
// re-zeroed on every launch/graph-replay).
__global__ __launch_bounds__(256) void k_prep(const float* __restrict__ whh,
                                              u16* __restrict__ Wf,
                                              u32* __restrict__ hexz,
                                              u32* __restrict__ flags) {
  int cell = blockIdx.x * 256 + threadIdx.x;  // 32768 cells, 8 f16 each
  int mt = cell >> 9, kt = (cell >> 6) & 7, l = cell & 63;
  int gr = mt * 16 + (l & 15);
  int c0 = kt * 32 + (l >> 4) * 8;
  const float4* src = (const float4*)(whh + (size_t)gr * 256 + c0);
  float4 a = src[0], b = src[1];
  u16 o[8] = { f2h(a.x), f2h(a.y), f2h(a.z), f2h(a.w),
               f2h(b.x), f2h(b.y), f2h(b.z), f2h(b.w) };
  *(uint4*)(Wf + (size_t)cell * 8) = *(uint4*)o;
  if (blockIdx.x < 32) hexz[blockIdx.x * 256 + threadIdx.x] = 0;  // h buf0 = 0
  if (blockIdx.x == 32 && threadIdx.x < 16) flags[threadIdx.x] = 0;
}

// ---------- kernel 2: xproj via bf16 MFMA, f16 out in k_rnn D-frag order -----
// xp2[t][bg][mt'][lane][r] with mt' = j16*4 + q  (q=gate, j16=row-block).
#define LDSPITCH 264
__global__ __launch_bounds__(256) void k_xproj(const int* __restrict__ x,
                                               const float* __restrict__ emb,
                                               const float* __restrict__ wih,
                                               const float* __restrict__ bih,
                                               const float* __restrict__ bhh,
                                               u16* __restrict__ xp2) {
  __shared__ u16 smA[64 * LDSPITCH];
  __shared__ u16 smB[64 * LDSPITCH];
  const int tn = blockIdx.x, t = blockIdx.y;
  const int tid = threadIdx.x;
  const int r = tid >> 2, q4 = tid & 3;

  { // stage A: emb rows (batch r, timestep t), fp32 -> bf16
    int eidx = x[r * T_LEN + t];
    const float4* src = (const float4*)(emb + (size_t)eidx * EDIM + q4 * 64);
    u16* dst = smA + r * LDSPITCH + q4 * 64;
    #pragma unroll
    for (int i = 0; i < 16; ++i) {
      float4 v = src[i];
      uint2 p;
      p.x = (u32)f2bf(v.x) | ((u32)f2bf(v.y) << 16);
      p.y = (u32)f2bf(v.z) | ((u32)f2bf(v.w) << 16);
      *(uint2*)&dst[i * 4] = p;
    }
  }
  { // stage B: w_ih rows g = tn*64 + r
    const float4* src = (const float4*)(wih + (size_t)(tn * 64 + r) * EDIM + q4 * 64);
    u16* dst = smB + r * LDSPITCH + q4 * 64;
    #pragma unroll
    for (int i = 0; i < 16; ++i) {
      float4 v = src[i];
      uint2 p;
      p.x = (u32)f2bf(v.x) | ((u32)f2bf(v.y) << 16);
      p.y = (u32)f2bf(v.z) | ((u32)f2bf(v.w) << 16);
      *(uint2*)&dst[i * 4] = p;
    }
  }
  __syncthreads();

  const int wv = tid >> 6, lane = tid & 63;
  const int lm = lane & 15, q = lane >> 4;
  f32x4 acc[4];
  #pragma unroll
  for (int nt = 0; nt < 4; ++nt) acc[nt] = (f32x4){0.f, 0.f, 0.f, 0.f};

  const u16* pa = smA + (wv * 16 + lm) * LDSPITCH + q * 8;
  const u16* pb = smB + lm * LDSPITCH + q * 8;
  #pragma unroll
  for (int ks = 0; ks < 8; ++ks) {
    short8 av = *(const short8*)(pa + ks * 32);
    #pragma unroll
    for (int nt = 0; nt < 4; ++nt) {
      short8 bv = *(const short8*)(pb + nt * 16 * LDSPITCH + ks * 32);
      acc[nt] = __builtin_amdgcn_mfma_f32_16x16x32_bf16(av, bv, acc[nt], 0, 0, 0);
    }
  }
  // D: row = batch = wv*16+q*4+rr, col = gate row g = tn*64+nt*16+lm.
  #pragma unroll
  for (int nt = 0; nt < 4; ++nt) {
    int g = tn * 64 + nt * 16 + lm;
    float bias = bih[g] + bhh[g];
    int gq = g >> 8, j16 = (g >> 4) & 15, qd = (g & 15) >> 2, rb = g & 3;
    int mtp = j16 * 4 + gq;
    #pragma unroll
    for (int rr = 0; rr < 4; ++rr) {
      int bl = q * 4 + rr;   // batch-in-group; bg = wv
      size_t idx = ((((size_t)t * 4 + wv) * 64 + mtp) * 64 + (qd * 16 + bl)) * 4 + rb;
      xp2[idx] = f2h(acc[nt][rr] + bias);
    }
  }
}

// ---------- kernel 3: recurrence, 16 WGs = (batch-group x output-quarter) ----
// WG wg: bg = wg&3 owns batches [bg*16,+16); qr = wg>>2 owns h dims
// [qr*64,+64)  (row-blocks j = qr*4 + jj, jj = wave&3).  Wave pair qp = wave>>2
// holds gates {i,f} (qp=0) or {g,o} (qp=1) for its jj; all 16 weight frags
// (2 m-tiles x 8 kt) live in registers.  Per step:
//   1. load B-frags of full h_t from exchange buf[t&1] (agent-scope, LLC)
//   2. 16 MFMA -> gate partials; swap the 2 missing gates via 8KB LDS tile
//   3. gates -> h pair; agent-store to buf[(t+1)&1]; vmcnt(0); barrier;
//      flag atomicAdd(+1); 3 lanes poll partner flags via atomicAdd(+0) RMW
//      (RMW = the HW-verified cross-XCD primitive); barrier.
// 2-buffer parity is safe: entering step t+2 requires all flags >= t+2, which
// orders the overwrite of buf[(t+1)&1] after every partner's t+1 reads.
// Spin budget is GLOBAL (2^22 polls/lane for the whole kernel): if the
// handshake ever stalls, the kernel finishes with wrong data instead of
// hanging the container.
__global__ __launch_bounds__(512) void k_rnn(const u16* __restrict__ Wf,
                                             const u16* __restrict__ xp2,
                                             u16* __restrict__ hex,   // 2 x 16384 u16
                                             u32* __restrict__ flags, // 16
                                             u16* __restrict__ hf) {  // [64][256] f16
  __shared__ f32x4 smX[512];   // gate-partial exchange: [(jj*2+qp)*64 + lane]
  const int wg = blockIdx.x;
  const int bg = wg & 3, qr = wg >> 2;
  const int tid = threadIdx.x;
  const int v = tid >> 6, l = tid & 63;
  const int jj = v & 3, qp = v >> 2;
  const int j = qr * 4 + jj;          // global row-block 0..15
  const int bl = l & 15, qd = l >> 4;

  // ---- all weights in RF: 2 m-tiles x 8 kt = 16 frags = 64 VGPRs ----
  half8 Wr[2][8];
  #pragma unroll
  for (int m = 0; m < 2; ++m) {
    const int mt = (2 * qp + m) * 16 + j;
    #pragma unroll
    for (int kt = 0; kt < 8; ++kt)
      Wr[m][kt] = *(const half8*)(Wf + ((size_t)(mt * 8 + kt) * 64 + l) * 8);
  }
  #pragma unroll
  for (int m = 0; m < 2; ++m)
    asm volatile("" : "+v"(Wr[m][0]), "+v"(Wr[m][1]), "+v"(Wr[m][2]), "+v"(Wr[m][3]),
                      "+v"(Wr[m][4]), "+v"(Wr[m][5]), "+v"(Wr[m][6]), "+v"(Wr[m][7]));

  int pid = 0;
  if (tid < 3) { int q2 = tid + (tid >= qr); pid = q2 * 4 + bg; }
  int budget = 1 << 22;   // global poll budget per lane (hang-safety)

  // element-index bases into hex (u16 units)
  const int rdofs = (bg * 16 + bl) * 256 + qd * 8;            // + par*16384 + kt*32
  const int wdim  = j * 16 + qd * 4 + 2 * qp;                 // even
  const int wrofs = (bg * 16 + bl) * 256 + wdim;              // + par*16384

  const u16* xq = xp2 + (size_t)bg * 16384 + (size_t)j * 1024 + l * 4 + qp * 2;
  u32 xg0 = *(const u32*)(xq);
  u32 xg1 = *(const u32*)(xq + 256);
  u32 xg2 = *(const u32*)(xq + 512);
  u32 xg3 = *(const u32*)(xq + 768);

  float cs[2] = {0.f, 0.f};

  for (int t = 0; t < T_LEN; ++t) {
    // 1. B-fragments of h_t: lane reads h[bl][kt*32 + qd*8 .. +8) agent-scope
    const u16* hbp = hex + (t & 1) * 16384 + rdofs;
    u64 lo[8], hi[8];
    #pragma unroll
    for (int kt = 0; kt < 8; ++kt) {
      lo[kt] = __hip_atomic_load((const u64*)(const void*)(hbp + kt * 32),
                                 __ATOMIC_RELAXED, __HIP_MEMORY_SCOPE_AGENT);
      hi[kt] = __hip_atomic_load((const u64*)(const void*)(hbp + kt * 32 + 4),
                                 __ATOMIC_RELAXED, __HIP_MEMORY_SCOPE_AGENT);
    }
    // 2. MFMA: acc[m] over kt; m = gate 2*qp+m for row-block j
    f32x4 acc0 = (f32x4){0.f, 0.f, 0.f, 0.f};
    f32x4 acc1 = (f32x4){0.f, 0.f, 0.f, 0.f};
    #pragma unroll
    for (int kt = 0; kt < 8; ++kt) {
      u64x2 bb; bb.x = lo[kt]; bb.y = hi[kt];
      half8 Bf = __builtin_bit_cast(half8, bb);
      acc0 = __builtin_amdgcn_mfma_f32_16x16x32_f16(Wr[0][kt], Bf, acc0, 0, 0, 0);
      acc1 = __builtin_amdgcn_mfma_f32_16x16x32_f16(Wr[1][kt], Bf, acc1, 0, 0, 0);
    }
    // gate-partial swap: qp0 exports i/f at r=2,3; qp1 exports g/o at r=0,1
    f32x4 e;
    if (qp == 0) { e[0] = acc0[2]; e[1] = acc0[3]; e[2] = acc1[2]; e[3] = acc1[3]; }
    else         { e[0] = acc0[0]; e[1] = acc0[1]; e[2] = acc1[0]; e[3] = acc1[1]; }
    smX[(jj * 2 + qp) * 64 + l] = e;
    __syncthreads();
    f32x4 prt = smX[(jj * 2 + (1 - qp)) * 64 + l];

    // 3. gates for rows r = 2*qp + {0,1}, batch bg*16+bl
    u32 pack = 0;
    #pragma unroll
    for (int u = 0; u < 2; ++u) {
      float zi, zf, zg, zo;
      if (qp == 0) { zi = acc0[u]; zf = acc1[u]; zg = prt[u];      zo = prt[2 + u]; }
      else         { zi = prt[u];  zf = prt[2 + u]; zg = acc0[2 + u]; zo = acc1[2 + u]; }
      zi += h2f((u16)(xg0 >> (16 * u)));
      zf += h2f((u16)(xg1 >> (16 * u)));
      zg += h2f((u16)(xg2 >> (16 * u)));
      zo += h2f((u16)(xg3 >> (16 * u)));
      cs[u] = sigf(zf) * cs[u] + sigf(zi) * tanhfast(zg);
      float hn = sigf(zo) * tanhfast(cs[u]);
      pack |= (u32)f2h(hn) << (16 * u);
    }

    if (t == T_LEN - 1) {
      *(u32*)(hf + wrofs) = pack;   // final h, plain store (kernel-end visible)
    } else {
      // publish own h pair to buf[(t+1)&1] (agent-scope)
      __hip_atomic_store((u32*)(void*)(hex + ((t + 1) & 1) * 16384 + wrofs), pack,
                         __ATOMIC_RELAXED, __HIP_MEMORY_SCOPE_AGENT);
      // prefetch next step's xproj while the store drains
      xq += 65536;
      xg0 = *(const u32*)(xq);
      xg1 = *(const u32*)(xq + 256);
      xg2 = *(const u32*)(xq + 512);
      xg3 = *(const u32*)(xq + 768);
      asm volatile("s_waitcnt vmcnt(0)" ::: "memory");  // own stores at coherent point
      __syncthreads();                                  // whole WG's stores done
      if (tid == 0) atomicAdd(&flags[wg], 1u);          // RMW: cross-XCD verified
      if (tid < 3) {
        while (budget > 0 &&
               atomicAdd(&flags[pid], 0u) <= (u32)t) {  // RMW poll at coherent point
          --budget;
        }
      }
      __syncthreads();
    }
  }
}

// ---------- kernel 4: backward single step + fc1 + fc2 ----------
__global__ __launch_bounds__(256) void k_tail(const int* __restrict__ x,
                                              const float* __restrict__ emb,
                                              const float* __restrict__ wihb,
                                              const float* __restrict__ bihb,
                                              const float* __restrict__ bhhb,
                                              const float* __restrict__ fc1w,
                                              const float* __restrict__ fc1b,
                                              const float* __restrict__ fc2w,
                                              const float* __restrict__ fc2b,
                                              const u16* __restrict__ hf,
                                              float* __restrict__ out) {
  const int b = blockIdx.x, tid = threadIdx.x;
  __shared__ float e[EDIM], hb[HDIM], hfl[HDIM], f1[24];
  e[tid]   = emb[(size_t)x[b * T_LEN + (T_LEN - 1)] * EDIM + tid];
  hfl[tid] = h2f(hf[b * HDIM + tid]);
  __syncthreads();

  float z[4];
  #pragma unroll
  for (int gq = 0; gq < 4; ++gq) {
    int g = gq * HDIM + tid;
    float s = bihb[g] + bhhb[g];
    const float4* wr = (const float4*)(wihb + (size_t)g * EDIM);
    #pragma unroll 8
    for (int k = 0; k < 64; ++k) {
      float4 w = wr[k];
      s += w.x * e[4 * k] + w.y * e[4 * k + 1] + w.z * e[4 * k + 2] + w.w * e[4 * k + 3];
    }
    z[gq] = s;
  }
  float cb = sigf(z[0]) * tanhfast(z[2]);   // c0 = 0
  hb[tid] = sigf(z[3]) * tanhfast(cb);
  __syncthreads();

  if (tid < 24) {
    float s = fc1b[tid];
    const float* w = fc1w + tid * 512;
    #pragma unroll 8
    for (int k = 0; k < HDIM; ++k) s += w[k] * hfl[k] + w[HDIM + k] * hb[k];
    f1[tid] = fmaxf(s, 0.f);
  }
  __syncthreads();
  if (tid < 2) {
    float s = fc2b[tid];
    #pragma unroll
    for (int k = 0; k < 24; ++k) s += fc2w[tid * 24 + k] * f1[k];
    out[b * 2 + tid] = s;
  }
}

// ---------- launch ----------
extern "C" void kernel_launch(void* const* d_in, const int* in_sizes, int n_in,
                              void* d_out, int out_size, void* d_ws, size_t ws_size,
                              hipStream_t stream) {
  const int*   x     = (const int*)  d_in[0];
  const float* emb   = (const float*)d_in[1];
  const float* wih_f = (const float*)d_in[2];
  const float* whh_f = (const float*)d_in[3];
  const float* bih_f = (const float*)d_in[4];
  const float* bhh_f = (const float*)d_in[5];
  const float* wih_b = (const float*)d_in[6];
  // d_in[7] = w_hh_b: unused (backward runs exactly one step from zero state)
  const float* bih_b = (const float*)d_in[8];
  const float* bhh_b = (const float*)d_in[9];
  const float* fc1w  = (const float*)d_in[10];
  const float* fc1b  = (const float*)d_in[11];
  const float* fc2w  = (const float*)d_in[12];
  const float* fc2b  = (const float*)d_in[13];
  float* out = (float*)d_out;

  // workspace: xp2 64 MiB | Wf 512 KiB | hex 64 KiB | hf16 32 KiB | flags 64 B
  char* ws = (char*)d_ws;
  u16*   xp2   = (u16*)ws;
  u16*   Wf    = (u16*)(ws + 67108864);
  u16*   hexb  = (u16*)(ws + 67633152);
  u16*   hf16  = (u16*)(ws + 67698688);
  u32*   flags = (u32*)(ws + 67731456);

  k_prep <<<128, 256, 0, stream>>>(whh_f, Wf, (u32*)hexb, flags);
  k_xproj<<<dim3(16, 512), 256, 0, stream>>>(x, emb, wih_f, bih_f, bhh_f, xp2);
  k_rnn  <<<16, 512, 0, stream>>>(Wf, xp2, hexb, flags, hf16);
  k_tail <<<BATCH, 256, 0, stream>>>(x, emb, wih_b, bih_b, bhh_b,
                                     fc1w, fc1b, fc2w, fc2b, hf16, out);
}

// Round 4
// 2202.382 us; speedup vs baseline: 1.4788x; 1.4788x over previous
//
#include <hip/hip_runtime.h>

typedef unsigned int  u32;
typedef unsigned short u16;
typedef unsigned long long u64;
typedef _Float16 half8 __attribute__((ext_vector_type(8)));
typedef short   short8 __attribute__((ext_vector_type(8)));
typedef float   f32x4  __attribute__((ext_vector_type(4)));

#define T_LEN 512
#define BATCH 64
#define EDIM  256
#define HDIM  256
#define G4    1024   // 4*H gate rows

// ---------- numeric helpers ----------
static __device__ __forceinline__ u16 f2bf(float f) {
  u32 u = __builtin_bit_cast(u32, f);
  u = (u + 0x7fffu + ((u >> 16) & 1u)) >> 16;   // RTNE
  return (u16)u;
}
static __device__ __forceinline__ u16 f2h(float a) {
  _Float16 ha = (_Float16)a;
  return __builtin_bit_cast(u16, ha);
}
static __device__ __forceinline__ float h2f(u16 a) {
  return (float)__builtin_bit_cast(_Float16, a);
}
static __device__ __forceinline__ float sigf(float x) {
  return 1.0f / (1.0f + __expf(-x));
}
static __device__ __forceinline__ float tanhfast(float x) {
  return 2.0f / (1.0f + __expf(-2.0f * x)) - 1.0f;
}

// ---------- kernel 1: pack W_hh_f into f16 MFMA A-frag order -----------------
// Wf[mt][kt][lane][ji]: flat ((mt*8+kt)*64+lane)*8+ji; value =
// W[mt*16+(lane&15)][kt*32+(lane>>4)*8+ji].
__global__ __launch_bounds__(256) void k_prep(const float* __restrict__ whh,
                                              u16* __restrict__ Wf) {
  int cell = blockIdx.x * 256 + threadIdx.x;  // 32768 cells, 8 f16 each
  int mt = cell >> 9, kt = (cell >> 6) & 7, l = cell & 63;
  int gr = mt * 16 + (l & 15);
  int c0 = kt * 32 + (l >> 4) * 8;
  const float4* src = (const float4*)(whh + (size_t)gr * 256 + c0);
  float4 a = src[0], b = src[1];
  u16 o[8] = { f2h(a.x), f2h(a.y), f2h(a.z), f2h(a.w),
               f2h(b.x), f2h(b.y), f2h(b.z), f2h(b.w) };
  *(uint4*)(Wf + (size_t)cell * 8) = *(uint4*)o;
}

// ---------- kernel 2: xproj via bf16 MFMA, f16 out in k_rnn D-frag order -----
// xp2[t][bg][mt'][lane][r] with mt' = j16*4 + q  (q=gate, j16=row-block).
// (IDENTICAL to the proven round-0 version.)
#define LDSPITCH 264
__global__ __launch_bounds__(256) void k_xproj(const int* __restrict__ x,
                                               const float* __restrict__ emb,
                                               const float* __restrict__ wih,
                                               const float* __restrict__ bih,
                                               const float* __restrict__ bhh,
                                               u16* __restrict__ xp2) {
  __shared__ u16 smA[64 * LDSPITCH];
  __shared__ u16 smB[64 * LDSPITCH];
  const int tn = blockIdx.x, t = blockIdx.y;
  const int tid = threadIdx.x;
  const int r = tid >> 2, q4 = tid & 3;

  { // stage A: emb rows (batch r, timestep t), fp32 -> bf16
    int eidx = x[r * T_LEN + t];
    const float4* src = (const float4*)(emb + (size_t)eidx * EDIM + q4 * 64);
    u16* dst = smA + r * LDSPITCH + q4 * 64;
    #pragma unroll
    for (int i = 0; i < 16; ++i) {
      float4 v = src[i];
      uint2 p;
      p.x = (u32)f2bf(v.x) | ((u32)f2bf(v.y) << 16);
      p.y = (u32)f2bf(v.z) | ((u32)f2bf(v.w) << 16);
      *(uint2*)&dst[i * 4] = p;
    }
  }
  { // stage B: w_ih rows g = tn*64 + r
    const float4* src = (const float4*)(wih + (size_t)(tn * 64 + r) * EDIM + q4 * 64);
    u16* dst = smB + r * LDSPITCH + q4 * 64;
    #pragma unroll
    for (int i = 0; i < 16; ++i) {
      float4 v = src[i];
      uint2 p;
      p.x = (u32)f2bf(v.x) | ((u32)f2bf(v.y) << 16);
      p.y = (u32)f2bf(v.z) | ((u32)f2bf(v.w) << 16);
      *(uint2*)&dst[i * 4] = p;
    }
  }
  __syncthreads();

  const int wv = tid >> 6, lane = tid & 63;
  const int lm = lane & 15, q = lane >> 4;
  f32x4 acc[4];
  #pragma unroll
  for (int nt = 0; nt < 4; ++nt) acc[nt] = (f32x4){0.f, 0.f, 0.f, 0.f};

  const u16* pa = smA + (wv * 16 + lm) * LDSPITCH + q * 8;
  const u16* pb = smB + lm * LDSPITCH + q * 8;
  #pragma unroll
  for (int ks = 0; ks < 8; ++ks) {
    short8 av = *(const short8*)(pa + ks * 32);
    #pragma unroll
    for (int nt = 0; nt < 4; ++nt) {
      short8 bv = *(const short8*)(pb + nt * 16 * LDSPITCH + ks * 32);
      acc[nt] = __builtin_amdgcn_mfma_f32_16x16x32_bf16(av, bv, acc[nt], 0, 0, 0);
    }
  }
  // D: row = batch = wv*16+q*4+rr, col = gate row g = tn*64+nt*16+lm.
  #pragma unroll
  for (int nt = 0; nt < 4; ++nt) {
    int g = tn * 64 + nt * 16 + lm;
    float bias = bih[g] + bhh[g];
    int gq = g >> 8, j16 = (g >> 4) & 15, qdd = (g & 15) >> 2, rb = g & 3;
    int mtp = j16 * 4 + gq;
    #pragma unroll
    for (int rr = 0; rr < 4; ++rr) {
      int bl = q * 4 + rr;   // batch-in-group; bg = wv
      size_t idx = ((((size_t)t * 4 + wv) * 64 + mtp) * 64 + (qdd * 16 + bl)) * 4 + rb;
      xp2[idx] = f2h(acc[nt][rr] + bias);
    }
  }
}

// ---------- kernel 3: recurrence, 4 WGs x 1024 thr, single in-CU barrier -----
// WG bg owns batches [bg*16,+16).  16 waves; wave v owns row-block j = v
// (h dims [j*16, j*16+16)), all 4 gates q.  Per lane: 4 h-elements/step
// (rows j*16 + qd*4 + r, batch bg*16 + bl) -- half the 8-wave layout's work.
// Weights (32 frags/wave): kt0-3 RF (16 frags, pinned), kt4-5 LDS-resident
// (wave-private slots, 128 KB), kt6-7 re-streamed from Wf each step via a
// laundered 32-bit OFFSET (keeps them out of the permanent register budget;
// XCD-L2-hot).  h double-buffered in LDS -> ONE barrier per step.
// xv (xproj) loads issued AFTER the MFMA chain: keeps peak VGPR <= 128 so the
// 1024-thread launch fits 4 waves/SIMD without hot-loop spills.
__global__ __launch_bounds__(1024) void k_rnn(const u16* __restrict__ Wf,
                                              const u16* __restrict__ xp2,
                                              u16* __restrict__ hf) {
  extern __shared__ u16 sm[];
  u16* smW = sm;               // 16 waves x 8 frags x 512 u16 = 65536 u16 (128 KB)
  u16* smH = sm + 65536;       // 2 x 4224 u16 (pitch 264) = 16.5 KB
  const int bg = blockIdx.x;
  const int tid = threadIdx.x;
  const int v = tid >> 6, l = tid & 63;
  const int j = v;                    // row-block 0..15
  const int bl = l & 15, qd = l >> 4;

  // ---- kt0-3 resident in RF ----
  half8 Wr[4][4];
  #pragma unroll
  for (int q = 0; q < 4; ++q)
    #pragma unroll
    for (int kt = 0; kt < 4; ++kt)
      Wr[q][kt] = *(const half8*)(Wf + ((size_t)((q * 16 + j) * 8 + kt) * 64 + l) * 8);
  #pragma unroll
  for (int q = 0; q < 4; ++q)
    asm volatile("" : "+v"(Wr[q][0]), "+v"(Wr[q][1]), "+v"(Wr[q][2]), "+v"(Wr[q][3]));

  // ---- kt4-5 staged to LDS (wave-private slots; no cross-wave deps) ----
  #pragma unroll
  for (int q = 0; q < 4; ++q)
    #pragma unroll
    for (int ki = 0; ki < 2; ++ki) {
      uint4 tv = *(const uint4*)(Wf + ((size_t)((q * 16 + j) * 8 + 4 + ki) * 64 + l) * 8);
      *(uint4*)(smW + ((size_t)(v * 8 + q * 2 + ki) * 512 + l * 8)) = tv;
    }

  { // zero h dbuf: 2 x 4224 u16 = 4224 u32
    u32* hz = (u32*)smH;
    for (int i = tid; i < 4224; i += 1024) hz[i] = 0;
  }
  __syncthreads();

  float c[4] = {0.f, 0.f, 0.f, 0.f};

  const u16* xbase = xp2 + (size_t)bg * 16384 + (size_t)j * 1024 + l * 4;  // += 65536/t
  const u16* hrd0 = smH + bl * 264 + qd * 8;
  const int  hwof = bl * 264 + j * 16 + qd * 4;
  // kt6-7 stream base: ((0*16+j)*8+6)*512 + l*8 u16; per-q stride 65536 u16.
  const u16* sb = Wf + ((size_t)(j * 8 + 6) * 64 + l) * 8;

  for (int t = 0; t < T_LEN; ++t) {
    // launder a 32-bit offset so LICM cannot hoist the 8 weight loads
    u32 zoff = 0;
    asm volatile("" : "+v"(zoff));
    const u16* sbl = sb + zoff;
    uint4 S6[4], S7[4];
    #pragma unroll
    for (int q = 0; q < 4; ++q) {
      S6[q] = *(const uint4*)(sbl + (size_t)q * 65536);
      S7[q] = *(const uint4*)(sbl + (size_t)q * 65536 + 512);
    }

    const u16* hb = hrd0 + (t & 1) * 4224;
    f32x4 acc[4];
    #pragma unroll
    for (int q = 0; q < 4; ++q) acc[q] = (f32x4){0.f, 0.f, 0.f, 0.f};
    #pragma unroll
    for (int kt = 0; kt < 8; ++kt) {
      half8 Bf = *(const half8*)(hb + kt * 32);
      #pragma unroll
      for (int q = 0; q < 4; ++q) {
        half8 Af;
        if (kt < 4)      Af = Wr[q][kt];
        else if (kt < 6) Af = *(const half8*)(smW + ((size_t)(v * 8 + q * 2 + (kt - 4)) * 512 + l * 8));
        else             Af = __builtin_bit_cast(half8, (kt == 6) ? S6[q] : S7[q]);
        acc[q] = __builtin_amdgcn_mfma_f32_16x16x32_f16(Af, Bf, acc[q], 0, 0, 0);
      }
    }

    // xp for this step (L2/L3-hot; issued post-MFMA to cap peak VGPRs)
    uint2 xv[4];
    #pragma unroll
    for (int q = 0; q < 4; ++q)
      xv[q] = *(const uint2*)(xbase + q * 256);

    // gates for rows j*16 + qd*4 + r, batch bg*16 + bl
    u32 lo = 0, hi = 0;
    #pragma unroll
    for (int r = 0; r < 4; ++r) {
      const int sh = 16 * (r & 1);
      float zi = acc[0][r] + h2f((u16)(((r < 2) ? xv[0].x : xv[0].y) >> sh));
      float zf = acc[1][r] + h2f((u16)(((r < 2) ? xv[1].x : xv[1].y) >> sh));
      float zg = acc[2][r] + h2f((u16)(((r < 2) ? xv[2].x : xv[2].y) >> sh));
      float zo = acc[3][r] + h2f((u16)(((r < 2) ? xv[3].x : xv[3].y) >> sh));
      c[r] = sigf(zf) * c[r] + sigf(zi) * tanhfast(zg);
      float hn = sigf(zo) * tanhfast(c[r]);
      u16 hv = f2h(hn);
      if (r < 2) lo |= (u32)hv << sh; else hi |= (u32)hv << sh;
    }
    if (t == T_LEN - 1) {
      *(uint2*)(hf + (size_t)(bg * 16 + bl) * 256 + j * 16 + qd * 4) = make_uint2(lo, hi);
    } else {
      *(uint2*)(smH + ((t + 1) & 1) * 4224 + hwof) = make_uint2(lo, hi);
    }
    xbase += 65536;
    __syncthreads();   // single barrier: next step reads the buffer just written
  }
}

// ---------- kernel 4: backward single step + fc1 + fc2 ----------
__global__ __launch_bounds__(256) void k_tail(const int* __restrict__ x,
                                              const float* __restrict__ emb,
                                              const float* __restrict__ wihb,
                                              const float* __restrict__ bihb,
                                              const float* __restrict__ bhhb,
                                              const float* __restrict__ fc1w,
                                              const float* __restrict__ fc1b,
                                              const float* __restrict__ fc2w,
                                              const float* __restrict__ fc2b,
                                              const u16* __restrict__ hf,
                                              float* __restrict__ out) {
  const int b = blockIdx.x, tid = threadIdx.x;
  __shared__ float e[EDIM], hb[HDIM], hfl[HDIM], f1[24];
  e[tid]   = emb[(size_t)x[b * T_LEN + (T_LEN - 1)] * EDIM + tid];
  hfl[tid] = h2f(hf[b * HDIM + tid]);
  __syncthreads();

  float z[4];
  #pragma unroll
  for (int gq = 0; gq < 4; ++gq) {
    int g = gq * HDIM + tid;
    float s = bihb[g] + bhhb[g];
    const float4* wr = (const float4*)(wihb + (size_t)g * EDIM);
    #pragma unroll 8
    for (int k = 0; k < 64; ++k) {
      float4 w = wr[k];
      s += w.x * e[4 * k] + w.y * e[4 * k + 1] + w.z * e[4 * k + 2] + w.w * e[4 * k + 3];
    }
    z[gq] = s;
  }
  float cb = sigf(z[0]) * tanhfast(z[2]);   // c0 = 0
  hb[tid] = sigf(z[3]) * tanhfast(cb);
  __syncthreads();

  if (tid < 24) {
    float s = fc1b[tid];
    const float* w = fc1w + tid * 512;
    #pragma unroll 8
    for (int k = 0; k < HDIM; ++k) s += w[k] * hfl[k] + w[HDIM + k] * hb[k];
    f1[tid] = fmaxf(s, 0.f);
  }
  __syncthreads();
  if (tid < 2) {
    float s = fc2b[tid];
    #pragma unroll
    for (int k = 0; k < 24; ++k) s += fc2w[tid * 24 + k] * f1[k];
    out[b * 2 + tid] = s;
  }
}

// ---------- launch ----------
extern "C" void kernel_launch(void* const* d_in, const int* in_sizes, int n_in,
                              void* d_out, int out_size, void* d_ws, size_t ws_size,
                              hipStream_t stream) {
  const int*   x     = (const int*)  d_in[0];
  const float* emb   = (const float*)d_in[1];
  const float* wih_f = (const float*)d_in[2];
  const float* whh_f = (const float*)d_in[3];
  const float* bih_f = (const float*)d_in[4];
  const float* bhh_f = (const float*)d_in[5];
  const float* wih_b = (const float*)d_in[6];
  // d_in[7] = w_hh_b: unused (backward runs exactly one step from zero state)
  const float* bih_b = (const float*)d_in[8];
  const float* bhh_b = (const float*)d_in[9];
  const float* fc1w  = (const float*)d_in[10];
  const float* fc1b  = (const float*)d_in[11];
  const float* fc2w  = (const float*)d_in[12];
  const float* fc2b  = (const float*)d_in[13];
  float* out = (float*)d_out;

  // workspace: xp2 64 MiB | Wf 512 KiB | hf16 32 KiB
  char* ws = (char*)d_ws;
  u16* xp2  = (u16*)ws;
  u16* Wf   = (u16*)(ws + 67108864);
  u16* hf16 = (u16*)(ws + 67108864 + 524288);

  k_prep <<<128, 256, 0, stream>>>(whh_f, Wf);
  k_xproj<<<dim3(16, 512), 256, 0, stream>>>(x, emb, wih_f, bih_f, bhh_f, xp2);
  k_rnn  <<<4, 1024, 147968, stream>>>(Wf, xp2, hf16);
  k_tail <<<BATCH, 256, 0, stream>>>(x, emb, wih_b, bih_b, bhh_b,
                                     fc1w, fc1b, fc2w, fc2b, hf16, out);
}